// Round 2
// baseline (504.682 us; speedup 1.0000x reference)
//
#include <hip/hip_runtime.h>

typedef unsigned short u16;
typedef unsigned int u32;
typedef __attribute__((ext_vector_type(8))) short short8;
typedef __attribute__((ext_vector_type(4))) float f32x4;
typedef __attribute__((ext_vector_type(16))) float f32x16;

#define BB 4
#define NN 128
#define DD 256
#define DFF 1024

__device__ __forceinline__ u16 f2b(float f) {
  union { float f; u32 u; } c; c.f = f;
  u32 x = c.u;
  return (u16)((x + 0x7FFFu + ((x >> 16) & 1u)) >> 16);
}
__device__ __forceinline__ float b2f(u16 u) {
  union { u32 u; float f; } c; c.u = ((u32)u) << 16;
  return c.f;
}

// ---------------- K0: transpose+convert graph FFN weights to bf16 ----------------
__global__ void k0_conv(const float* __restrict__ Wgf1, const float* __restrict__ Wgf2,
                        u16* __restrict__ W1t, u16* __restrict__ W2t) {
  int i = blockIdx.x * 256 + threadIdx.x;  // 0..262143
  int n1 = i >> 8, k1 = i & 255;
  W1t[i] = f2b(Wgf1[k1 * DFF + n1]);
  int n2 = i >> 10, k2 = i & 1023;
  W2t[i] = f2b(Wgf2[k2 * DD + n2]);
}

// ---------------- K1/K3a: three fused 256x256 projections, 2 rows/block ----------------
__global__ __launch_bounds__(256) void k_proj3(
    const float* __restrict__ in,
    const float* __restrict__ W0, const float* __restrict__ c0,
    const float* __restrict__ W1, const float* __restrict__ c1,
    const float* __restrict__ W2, const float* __restrict__ c2,
    float* __restrict__ o0, float* __restrict__ o1, float* __restrict__ o2) {
  __shared__ float row0[DD], row1[DD];
  const int t = threadIdx.x; const int r = blockIdx.x * 2;
  row0[t] = in[r * DD + t];
  row1[t] = in[(r + 1) * DD + t];
  __syncthreads();
  float a00 = c0[t], a01 = c1[t], a02 = c2[t];
  float a10 = a00, a11 = a01, a12 = a02;
  for (int c = 0; c < DD; ++c) {
    float w0 = W0[c * DD + t], w1 = W1[c * DD + t], w2 = W2[c * DD + t];
    float x0 = row0[c], x1 = row1[c];
    a00 += x0 * w0; a10 += x1 * w0;
    a01 += x0 * w1; a11 += x1 * w1;
    a02 += x0 * w2; a12 += x1 * w2;
  }
  o0[r * DD + t] = a00; o1[r * DD + t] = a01; o2[r * DD + t] = a02;
  o0[(r + 1) * DD + t] = a10; o1[(r + 1) * DD + t] = a11; o2[(r + 1) * DD + t] = a12;
}

// ---------------- K2: fused relation attention, one block per (b,x) ----------------
__global__ __launch_bounds__(256) void k2_attn(
    const float* __restrict__ bg, const float* __restrict__ qg,
    const float* __restrict__ kg, const float* __restrict__ vg,
    const float* __restrict__ Wrk, const float* __restrict__ brk,
    const float* __restrict__ Wrv, const float* __restrict__ brv,
    float* __restrict__ attn) {
  extern __shared__ char smem[];
  u16* bgt = (u16*)smem;                     // [128][260] bf16
  float* qs = (float*)(smem + 66560);        // [256]
  float* U  = (float*)(smem + 67584);        // [256][8]  (reused as Pg)
  float* sc = (float*)(smem + 75776);        // [128][8]  scores -> p
  float* cb = (float*)(smem + 79872);        // [8]
  const int t = threadIdx.x;
  const int blk = blockIdx.x;                // b*128 + x
  const int b = blk >> 7;
  const float* bgbase = bg + (long)blk * (NN * DD);

  qs[t] = qg[blk * DD + t];
  if (t < 8) {
    float s = 0.f;
    #pragma unroll
    for (int d = 0; d < 32; ++d) s += brk[t * 32 + d] * qg[blk * DD + t * 32 + d];
    cb[t] = s;
  }
  for (int i = 0; i < 32; ++i) {
    int e4 = i * 256 + t;
    float4 vv = *(const float4*)(bgbase + (long)e4 * 4);
    int e = e4 * 4; int row = e >> 8, col = e & 255;
    u32 p0 = (u32)f2b(vv.x) | ((u32)f2b(vv.y) << 16);
    u32 p1 = (u32)f2b(vv.z) | ((u32)f2b(vv.w) << 16);
    *(u32*)(bgt + row * 260 + col) = p0;
    *(u32*)(bgt + row * 260 + col + 2) = p1;
  }
  __syncthreads();
  {
    const float* wr = Wrk + t * DD;
    #pragma unroll
    for (int h = 0; h < 8; ++h) {
      float s = 0.f;
      #pragma unroll
      for (int d = 0; d < 32; ++d) s += wr[h * 32 + d] * qs[h * 32 + d];
      U[t * 8 + h] = s;
    }
  }
  __syncthreads();
  {
    const int h = t & 7, y0 = t >> 3;
    #pragma unroll
    for (int yy = 0; yy < 4; ++yy) {
      int y = y0 + yy * 32;
      float s = cb[h];
      const float* kr = kg + (long)(b * NN + y) * DD + h * 32;
      const float* qh = qs + h * 32;
      #pragma unroll
      for (int d = 0; d < 32; ++d) s += qh[d] * kr[d];
      const u16* br = bgt + y * 260;
      for (int c = 0; c < 256; c += 2) {
        u32 pk = *(const u32*)(br + c);
        s += b2f((u16)pk) * U[c * 8 + h] + b2f((u16)(pk >> 16)) * U[(c + 1) * 8 + h];
      }
      sc[y * 8 + h] = s * 0.1767766952966369f;
    }
  }
  __syncthreads();
  {
    const int h = t >> 5, ln = t & 31;
    float v0 = sc[ln * 8 + h], v1 = sc[(ln + 32) * 8 + h];
    float v2 = sc[(ln + 64) * 8 + h], v3 = sc[(ln + 96) * 8 + h];
    float mx = fmaxf(fmaxf(v0, v1), fmaxf(v2, v3));
    #pragma unroll
    for (int m = 1; m < 32; m <<= 1) mx = fmaxf(mx, __shfl_xor(mx, m, 32));
    float e0 = __expf(v0 - mx), e1 = __expf(v1 - mx);
    float e2 = __expf(v2 - mx), e3 = __expf(v3 - mx);
    float sm = e0 + e1 + e2 + e3;
    #pragma unroll
    for (int m = 1; m < 32; m <<= 1) sm += __shfl_xor(sm, m, 32);
    float inv = 1.f / sm;
    sc[ln * 8 + h] = e0 * inv; sc[(ln + 32) * 8 + h] = e1 * inv;
    sc[(ln + 64) * 8 + h] = e2 * inv; sc[(ln + 96) * 8 + h] = e3 * inv;
  }
  __syncthreads();
  {
    float acc[8];
    #pragma unroll
    for (int h = 0; h < 8; ++h) acc[h] = 0.f;
    for (int y = 0; y < 128; ++y) {
      float bv = b2f(bgt[y * 260 + t]);
      const float* pr = sc + y * 8;
      #pragma unroll
      for (int h = 0; h < 8; ++h) acc[h] += pr[h] * bv;
    }
    #pragma unroll
    for (int h = 0; h < 8; ++h) U[t * 8 + h] = acc[h];
  }
  __syncthreads();
  {
    const int h = t >> 5;
    float av = 0.f;
    for (int y = 0; y < 128; ++y) av += sc[y * 8 + h] * vg[(long)(b * NN + y) * DD + t];
    float ag = 0.f;
    for (int c = 0; c < 256; ++c) ag += U[c * 8 + h] * Wrv[c * DD + t];
    attn[blk * DD + t] = av + ag + brv[t];
  }
}

// ---------------- K3b: node branch, 2 rows/block ----------------
__global__ __launch_bounds__(256) void k3_node(
    const float* __restrict__ x, const float* __restrict__ x2,
    const float* __restrict__ W1, const float* __restrict__ b1,
    const float* __restrict__ W2, const float* __restrict__ b2,
    const float* __restrict__ g1, const float* __restrict__ beta1,
    const float* __restrict__ g2, const float* __restrict__ beta2,
    float* __restrict__ outx) {
  __shared__ float xs[2][DD];
  __shared__ float h1[2][DFF];
  __shared__ float red[2][8];
  const int t = threadIdx.x; const int r = blockIdx.x * 2;
  float xv0 = x[r * DD + t] + x2[r * DD + t];
  float xv1 = x[(r + 1) * DD + t] + x2[(r + 1) * DD + t];
  float s0 = xv0, q0 = xv0 * xv0, s1 = xv1, q1 = xv1 * xv1;
  #pragma unroll
  for (int m = 1; m < 64; m <<= 1) {
    s0 += __shfl_xor(s0, m); q0 += __shfl_xor(q0, m);
    s1 += __shfl_xor(s1, m); q1 += __shfl_xor(q1, m);
  }
  if ((t & 63) == 0) {
    int wi = t >> 6;
    red[0][wi] = s0; red[0][4 + wi] = q0;
    red[1][wi] = s1; red[1][4 + wi] = q1;
  }
  __syncthreads();
  s0 = red[0][0] + red[0][1] + red[0][2] + red[0][3];
  q0 = red[0][4] + red[0][5] + red[0][6] + red[0][7];
  s1 = red[1][0] + red[1][1] + red[1][2] + red[1][3];
  q1 = red[1][4] + red[1][5] + red[1][6] + red[1][7];
  float mn0 = s0 * (1.f / 256.f), vr0 = q0 * (1.f / 256.f) - mn0 * mn0;
  float mn1 = s1 * (1.f / 256.f), vr1 = q1 * (1.f / 256.f) - mn1 * mn1;
  float rs0 = rsqrtf(vr0 + 1e-5f), rs1 = rsqrtf(vr1 + 1e-5f);
  float xn0 = (xv0 - mn0) * rs0 * g1[t] + beta1[t];
  float xn1v = (xv1 - mn1) * rs1 * g1[t] + beta1[t];
  xs[0][t] = xn0; xs[1][t] = xn1v;
  __syncthreads();
  #pragma unroll
  for (int i = 0; i < 4; ++i) {
    int j = i * 256 + t;
    float hv0 = b1[j], hv1 = hv0;
    for (int c = 0; c < DD; ++c) {
      float wv = W1[c * DFF + j];
      hv0 += xs[0][c] * wv; hv1 += xs[1][c] * wv;
    }
    h1[0][j] = hv0 > 0.f ? hv0 : 0.f;
    h1[1][j] = hv1 > 0.f ? hv1 : 0.f;
  }
  __syncthreads();
  float yv0 = b2[t], yv1 = yv0;
  for (int c = 0; c < DFF; ++c) {
    float wv = W2[c * DD + t];
    yv0 += h1[0][c] * wv; yv1 += h1[1][c] * wv;
  }
  float t20 = xn0 + yv0, t21 = xn1v + yv1;
  s0 = t20; q0 = t20 * t20; s1 = t21; q1 = t21 * t21;
  #pragma unroll
  for (int m = 1; m < 64; m <<= 1) {
    s0 += __shfl_xor(s0, m); q0 += __shfl_xor(q0, m);
    s1 += __shfl_xor(s1, m); q1 += __shfl_xor(q1, m);
  }
  if ((t & 63) == 0) {
    int wi = t >> 6;
    red[0][wi] = s0; red[0][4 + wi] = q0;
    red[1][wi] = s1; red[1][4 + wi] = q1;
  }
  __syncthreads();
  s0 = red[0][0] + red[0][1] + red[0][2] + red[0][3];
  q0 = red[0][4] + red[0][5] + red[0][6] + red[0][7];
  s1 = red[1][0] + red[1][1] + red[1][2] + red[1][3];
  q1 = red[1][4] + red[1][5] + red[1][6] + red[1][7];
  mn0 = s0 * (1.f / 256.f); vr0 = q0 * (1.f / 256.f) - mn0 * mn0;
  mn1 = s1 * (1.f / 256.f); vr1 = q1 * (1.f / 256.f) - mn1 * mn1;
  rs0 = rsqrtf(vr0 + 1e-5f); rs1 = rsqrtf(vr1 + 1e-5f);
  outx[r * DD + t] = (t20 - mn0) * rs0 * g2[t] + beta2[t];
  outx[(r + 1) * DD + t] = (t21 - mn1) * rs1 * g2[t] + beta2[t];
}

// ---------------- K4: graph branch, 32x32x16 MFMA, B-frags from L2 ----------------
// 512 blocks x 512 thr (8 waves).  Wave grid: 8-way N-split (no B duplication).
// LDS: As[128][256] bf16 (swz) + Fs[128][256] bf16 (swz) = 128 KB.
// Swizzle: 16B-chunk index c' = c ^ (row&31)  -> conflict-free b128 reads.
__global__ __launch_bounds__(512, 2) void k4_graph(
    const float* __restrict__ bg, const float* __restrict__ aL, const float* __restrict__ aR,
    const u16* __restrict__ W1t, const float* __restrict__ bgf1,
    const u16* __restrict__ W2t, const float* __restrict__ bgf2,
    const float* __restrict__ gg1, const float* __restrict__ betag1,
    const float* __restrict__ gg2, const float* __restrict__ betag2,
    float* __restrict__ outbg) {
  extern __shared__ u16 lds[];
  u16* As = lds;            // [128][256]
  u16* Fs = lds + 32768;    // [128][256]
  const int t = threadIdx.x;
  const long r0 = (long)blockIdx.x * 128;

  {  // phase 0: As = bf16(LN(bg + aL + aR)), swizzled
    const int row = t >> 2, sub = t & 3;
    const long r = r0 + row;
    const int bx = (int)(r >> 7);
    const int by = (int)(((r >> 14) << 7) | (r & 127));
    const float4* pb = (const float4*)(bg + r * 256 + sub * 64);
    const float4* pl = (const float4*)(aL + (long)bx * 256 + sub * 64);
    const float4* pr = (const float4*)(aR + (long)by * 256 + sub * 64);
    float v[64];
    float s = 0.f, sq = 0.f;
    #pragma unroll
    for (int i = 0; i < 16; ++i) {
      float4 a = pb[i], b = pl[i], c = pr[i];
      float x0 = a.x + b.x + c.x, x1 = a.y + b.y + c.y;
      float x2v = a.z + b.z + c.z, x3 = a.w + b.w + c.w;
      v[4 * i] = x0; v[4 * i + 1] = x1; v[4 * i + 2] = x2v; v[4 * i + 3] = x3;
      s += x0 + x1 + x2v + x3;
      sq += x0 * x0 + x1 * x1 + x2v * x2v + x3 * x3;
    }
    s += __shfl_xor(s, 1); s += __shfl_xor(s, 2);
    sq += __shfl_xor(sq, 1); sq += __shfl_xor(sq, 2);
    float mean = s * (1.f / 256.f);
    float var = sq * (1.f / 256.f) - mean * mean;
    float rs = rsqrtf(var + 1e-5f);
    const float* g = gg1 + sub * 64; const float* be = betag1 + sub * 64;
    #pragma unroll
    for (int j8 = 0; j8 < 8; ++j8) {
      short8 pk;
      #pragma unroll
      for (int e = 0; e < 8; ++e) {
        int j = j8 * 8 + e;
        pk[e] = (short)f2b((v[j] - mean) * rs * g[j] + be[j]);
      }
      int c = (sub * 8 + j8) ^ (row & 31);
      *(short8*)(As + row * 256 + c * 8) = pk;
    }
  }

  const int l = t & 63, w = t >> 6, lm = l & 31, hl = l >> 5;
  const int n = w * 32 + lm;  // wave's 32-col stripe

  f32x16 acc2[4];
  #pragma unroll
  for (int mt = 0; mt < 4; ++mt)
    #pragma unroll
    for (int r = 0; r < 16; ++r) acc2[mt][r] = 0.f;

  const u16* bp2 = W2t + n * 1024 + hl * 8;

  for (int nc = 0; nc < 4; ++nc) {
    __syncthreads();  // Fs free (prev GEMM2 done), As ready on first iter
    // --- GEMM1: F[:, nc*256 + n] chunk ---
    f32x16 acc1[4];
    {
      float bias = bgf1[nc * 256 + n];
      #pragma unroll
      for (int mt = 0; mt < 4; ++mt)
        #pragma unroll
        for (int r = 0; r < 16; ++r) acc1[mt][r] = bias;
    }
    const u16* bp1 = W1t + (nc * 256 + n) * 256 + hl * 8;
    #pragma unroll
    for (int kk = 0; kk < 16; ++kk) {
      short8 bfrag = *(const short8*)(bp1 + kk * 16);
      #pragma unroll
      for (int mt = 0; mt < 4; ++mt) {
        short8 afrag = *(const short8*)(As + (mt * 32 + lm) * 256 + ((kk * 2 + hl) ^ lm) * 8);
        acc1[mt] = __builtin_amdgcn_mfma_f32_32x32x16_bf16(afrag, bfrag, acc1[mt], 0, 0, 0);
      }
    }
    // relu -> Fs (scalar u16, swizzled)
    #pragma unroll
    for (int mt = 0; mt < 4; ++mt) {
      #pragma unroll
      for (int r = 0; r < 16; ++r) {
        int row = mt * 32 + (r & 3) + 8 * (r >> 2) + 4 * hl;
        float vv = fmaxf(acc1[mt][r], 0.f);
        Fs[row * 256 + ((n >> 3) ^ (row & 31)) * 8 + (n & 7)] = f2b(vv);
      }
    }
    __syncthreads();
    // --- GEMM2: acc2 += F_chunk @ W2_chunk ---
    #pragma unroll
    for (int kk = 0; kk < 16; ++kk) {
      short8 bfrag = *(const short8*)(bp2 + nc * 256 + kk * 16);
      #pragma unroll
      for (int mt = 0; mt < 4; ++mt) {
        short8 afrag = *(const short8*)(Fs + (mt * 32 + lm) * 256 + ((kk * 2 + hl) ^ lm) * 8);
        acc2[mt] = __builtin_amdgcn_mfma_f32_32x32x16_bf16(afrag, bfrag, acc2[mt], 0, 0, 0);
      }
    }
  }
  __syncthreads();

  // ---- Epilogue: t2 = bg1 + y + bgf2; out = LN(t2)*gg2+betag2
  const float gn = gg2[n], btn = betag2[n], bf2 = bgf2[n];
  float vals[4][16];
  #pragma unroll
  for (int mt = 0; mt < 4; ++mt) {
    #pragma unroll
    for (int r = 0; r < 16; ++r) {
      int row = mt * 32 + (r & 3) + 8 * (r >> 2) + 4 * hl;
      float res = b2f(As[row * 256 + ((n >> 3) ^ (row & 31)) * 8 + (n & 7)]);
      vals[mt][r] = acc2[mt][r] + bf2 + res;
    }
  }
  float* red_s = (float*)Fs;        // [8][128]
  float* red_q = red_s + 1024;      // [8][128]
  float* mrs   = red_q + 1024;      // [128][2]
  #pragma unroll
  for (int mt = 0; mt < 4; ++mt) {
    #pragma unroll
    for (int r = 0; r < 16; ++r) {
      float s = vals[mt][r];
      float q = s * s;
      #pragma unroll
      for (int msk = 1; msk < 32; msk <<= 1) {
        s += __shfl_xor(s, msk, 32);
        q += __shfl_xor(q, msk, 32);
      }
      if (lm == 0) {
        int row = mt * 32 + (r & 3) + 8 * (r >> 2) + 4 * hl;
        red_s[w * 128 + row] = s;
        red_q[w * 128 + row] = q;
      }
    }
  }
  __syncthreads();
  if (t < 128) {
    float s = 0.f, q = 0.f;
    #pragma unroll
    for (int w8 = 0; w8 < 8; ++w8) { s += red_s[w8 * 128 + t]; q += red_q[w8 * 128 + t]; }
    float mean = s * (1.f / 256.f);
    float var = q * (1.f / 256.f) - mean * mean;
    mrs[2 * t] = mean; mrs[2 * t + 1] = rsqrtf(var + 1e-5f);
  }
  __syncthreads();
  #pragma unroll
  for (int mt = 0; mt < 4; ++mt) {
    #pragma unroll
    for (int r = 0; r < 16; ++r) {
      int row = mt * 32 + (r & 3) + 8 * (r >> 2) + 4 * hl;
      float mean = mrs[2 * row], rstd = mrs[2 * row + 1];
      outbg[(r0 + row) * 256 + n] = (vals[mt][r] - mean) * rstd * gn + btn;
    }
  }
}

// ---------------- host ----------------
extern "C" void kernel_launch(void* const* d_in, const int* in_sizes, int n_in,
                              void* d_out, int out_size, void* d_ws, size_t ws_size,
                              hipStream_t stream) {
  const float* x      = (const float*)d_in[0];
  const float* bg     = (const float*)d_in[1];
  const float* Wq     = (const float*)d_in[3];  const float* bq     = (const float*)d_in[4];
  const float* Wk     = (const float*)d_in[5];  const float* bk     = (const float*)d_in[6];
  const float* Wv     = (const float*)d_in[7];  const float* bv     = (const float*)d_in[8];
  const float* Wo     = (const float*)d_in[9];  const float* bo     = (const float*)d_in[10];
  const float* Wleft  = (const float*)d_in[11]; const float* bleft  = (const float*)d_in[12];
  const float* Wright = (const float*)d_in[13]; const float* bright = (const float*)d_in[14];
  const float* Wrk    = (const float*)d_in[15]; const float* brk    = (const float*)d_in[16];
  const float* Wrv    = (const float*)d_in[17]; const float* brv    = (const float*)d_in[18];
  const float* W1     = (const float*)d_in[19]; const float* b1     = (const float*)d_in[20];
  const float* W2     = (const float*)d_in[21]; const float* b2     = (const float*)d_in[22];
  const float* Wgf1   = (const float*)d_in[23]; const float* bgf1   = (const float*)d_in[24];
  const float* Wgf2   = (const float*)d_in[25]; const float* bgf2   = (const float*)d_in[26];
  const float* g1     = (const float*)d_in[27]; const float* g2     = (const float*)d_in[28];
  const float* gg1    = (const float*)d_in[29]; const float* gg2    = (const float*)d_in[30];
  const float* beta1  = (const float*)d_in[31]; const float* beta2  = (const float*)d_in[32];
  const float* betag1 = (const float*)d_in[33]; const float* betag2 = (const float*)d_in[34];

  float* ws   = (float*)d_ws;
  float* q    = ws;
  float* k    = ws + 131072;
  float* v    = ws + 262144;
  float* attn = ws + 393216;
  float* x2   = ws + 524288;
  float* aL   = ws + 655360;
  float* aR   = ws + 786432;
  u16* W1t = (u16*)(ws + 917504);
  u16* W2t = W1t + 262144;

  float* outx  = (float*)d_out;
  float* outbg = outx + 131072;

  hipFuncSetAttribute((const void*)k2_attn,  hipFuncAttributeMaxDynamicSharedMemorySize, 79904);
  hipFuncSetAttribute((const void*)k4_graph, hipFuncAttributeMaxDynamicSharedMemorySize, 131072);

  k0_conv <<<1024, 256, 0, stream>>>(Wgf1, Wgf2, W1t, W2t);
  k_proj3 <<<256, 256, 0, stream>>>(x, Wq, bq, Wk, bk, Wv, bv, q, k, v);
  k2_attn <<<512, 256, 79904, stream>>>(bg, q, k, v, Wrk, brk, Wrv, brv, attn);
  k_proj3 <<<256, 256, 0, stream>>>(attn, Wo, bo, Wleft, bleft, Wright, bright, x2, aL, aR);
  k3_node <<<256, 256, 0, stream>>>(x, x2, W1, b1, W2, b2, g1, beta1, g2, beta2, outx);
  k4_graph<<<512, 512, 131072, stream>>>(bg, aL, aR, W1t, bgf1, W2t, bgf2,
                                         gg1, betag1, gg2, betag2, outbg);
}